// Round 1
// baseline (5154.709 us; speedup 1.0000x reference)
//
#include <hip/hip_runtime.h>
#include <math.h>

constexpr int NB = 8, NC = 256, NE = 512, NH = 64, NW = 64, NHW = NH * NW;
constexpr int STEPS = 6;

__device__ __forceinline__ float sigm_(float x) { return 1.f / (1.f + expf(-x)); }
__device__ __forceinline__ float gelu_(float x) {
    return 0.5f * x * (1.f + erff(x * 0.70710678118654752f));
}

// ---------------- pooled = mean_{h,w} u : one block per (b,c) ----------------
__global__ void pool_kernel(const float* __restrict__ u, float* __restrict__ pooled) {
    const int bc = blockIdx.x;
    const float* base = u + (size_t)bc * NHW;
    const int tid = threadIdx.x;
    float s = 0.f;
#pragma unroll
    for (int i = 0; i < 4; ++i) {
        const float4 v = *reinterpret_cast<const float4*>(base + i * 1024 + tid * 4);
        s += v.x + v.y + v.z + v.w;
    }
#pragma unroll
    for (int off = 32; off > 0; off >>= 1) s += __shfl_down(s, off, 64);
    __shared__ float red[4];
    if ((tid & 63) == 0) red[tid >> 6] = s;
    __syncthreads();
    if (tid == 0) pooled[bc] = (red[0] + red[1] + red[2] + red[3]) * (1.f / NHW);
}

// ---------------- h = h*f + i*c on pooled features : one block per b ----------------
__global__ void h_kernel(const float* __restrict__ pooled,
                         const float* __restrict__ wf, const float* __restrict__ bfv,
                         const float* __restrict__ wi, const float* __restrict__ biv,
                         const float* __restrict__ wc, const float* __restrict__ bcv,
                         float* __restrict__ h, const int first) {
    const int b = blockIdx.x;
    const int c = threadIdx.x;
    __shared__ float sp[NC];
    sp[c] = pooled[b * NC + c];
    __syncthreads();
    float af = bfv[c], ai = biv[c], ac = bcv[c];
    for (int k = 0; k < NC; ++k) {
        const float p = sp[k];
        af = fmaf(p, wf[k * NC + c], af);
        ai = fmaf(p, wi[k * NC + c], ai);
        ac = fmaf(p, wc[k * NC + c], ac);
    }
    const float f  = sigm_(af);
    const float ii = sigm_(ai);
    const float cc = tanhf(ac);
    const float hold = first ? 0.f : h[b * NC + c];
    h[b * NC + c] = hold * f + ii * cc;
}

// ---------------- fused: stencil + MLP + memory/forcing + Euler + (RMSNorm) ----------------
// block = (b, row y); 256 threads; thread microtile: 4 e/c values x 4 pixels.
__global__ __launch_bounds__(256) void update_kernel(
    const float* __restrict__ uin, float* __restrict__ uout,
    const float* __restrict__ forcing, const float* __restrict__ dlog,
    const float* __restrict__ w1, const float* __restrict__ b1,
    const float* __restrict__ w2, const float* __restrict__ b2,
    const float* __restrict__ hbuf, const float* __restrict__ nsc,
    const float* __restrict__ p_logdt, const float* __restrict__ p_am,
    const float* __restrict__ p_af, const int do_norm)
{
    __shared__ float su[64][64];   // u k-chunk (row y, 64 channels x 64 px)
    __shared__ float sw[64][64];   // w1 / w2 staging
    __shared__ float sh[64][64];   // gelu(hdn) e-chunk
    __shared__ float inv64[64];

    const int tid = threadIdx.x;
    const int pg = tid & 15, eg = tid >> 4;
    const int x0 = pg * 4;
    const int b = blockIdx.x >> 6;
    const int y = blockIdx.x & 63;

    const float dt = fminf(fmaxf(expf(p_logdt[0]), 0.01f), 0.3f);
    const float am = p_am[0], afc = p_af[0];

    const size_t plane = (size_t)b * NC * NHW;
    const float* ub = uin + plane;

    float racc[4][4][4];  // [cchunk][jc][ip] -> react accumulator, later u_new
#pragma unroll
    for (int a = 0; a < 4; ++a)
#pragma unroll
        for (int j = 0; j < 4; ++j)
#pragma unroll
            for (int i = 0; i < 4; ++i) racc[a][j][i] = 0.f;

    // ================= MLP: for each e-chunk of 64 =================
    for (int ec = 0; ec < 8; ++ec) {
        float acc[4][4];
#pragma unroll
        for (int j = 0; j < 4; ++j)
#pragma unroll
            for (int i = 0; i < 4; ++i) acc[j][i] = 0.f;

        // GEMM1: hdn[e, x] = sum_k u[k, x] * w1[k, e]
        for (int kc = 0; kc < 4; ++kc) {
            __syncthreads();
#pragma unroll
            for (int i = 0; i < 16; ++i) {
                const int idx = i * 256 + tid;
                const int r = idx >> 6, q = idx & 63;
                su[r][q] = ub[(size_t)(kc * 64 + r) * NHW + (size_t)y * NW + q];
                sw[r][q] = w1[(size_t)(kc * 64 + r) * NE + ec * 64 + q];
            }
            __syncthreads();
#pragma unroll 8
            for (int kk = 0; kk < 64; ++kk) {
                const float4 a4 = *reinterpret_cast<const float4*>(&su[kk][x0]);
                const float4 w4 = *reinterpret_cast<const float4*>(&sw[kk][eg * 4]);
                const float av[4] = {a4.x, a4.y, a4.z, a4.w};
                const float wv[4] = {w4.x, w4.y, w4.z, w4.w};
#pragma unroll
                for (int j = 0; j < 4; ++j)
#pragma unroll
                    for (int i = 0; i < 4; ++i)
                        acc[j][i] = fmaf(wv[j], av[i], acc[j][i]);
            }
        }
        // bias + exact GELU -> sh
#pragma unroll
        for (int j = 0; j < 4; ++j) {
            const float bb = b1[ec * 64 + eg * 4 + j];
            float4 hv;
            hv.x = gelu_(acc[j][0] + bb);
            hv.y = gelu_(acc[j][1] + bb);
            hv.z = gelu_(acc[j][2] + bb);
            hv.w = gelu_(acc[j][3] + bb);
            *reinterpret_cast<float4*>(&sh[eg * 4 + j][x0]) = hv;
        }
        // GEMM2: react[c, x] += sum_e sh[e, x] * w2[e, c]
        for (int cch = 0; cch < 4; ++cch) {
            __syncthreads();   // sh writes complete; previous sw readers done
#pragma unroll
            for (int i = 0; i < 16; ++i) {
                const int idx = i * 256 + tid;
                const int r = idx >> 6, q = idx & 63;
                sw[r][q] = w2[(size_t)(ec * 64 + r) * NC + cch * 64 + q];
            }
            __syncthreads();
#pragma unroll 8
            for (int ee = 0; ee < 64; ++ee) {
                const float4 h4 = *reinterpret_cast<const float4*>(&sh[ee][x0]);
                const float4 w4 = *reinterpret_cast<const float4*>(&sw[ee][eg * 4]);
                const float hv2[4] = {h4.x, h4.y, h4.z, h4.w};
                const float wv2[4] = {w4.x, w4.y, w4.z, w4.w};
#pragma unroll
                for (int j = 0; j < 4; ++j)
#pragma unroll
                    for (int i = 0; i < 4; ++i)
                        racc[cch][j][i] = fmaf(wv2[j], hv2[i], racc[cch][j][i]);
            }
        }
    }

    // ================= stencil + du + Euler update =================
    const float* frow = forcing + plane + (size_t)y * NW;
    for (int cch = 0; cch < 4; ++cch) {
        __syncthreads();
#pragma unroll
        for (int i = 0; i < 16; ++i) {
            const int idx = i * 256 + tid;
            const int r = idx >> 6, q = idx & 63;
            su[r][q] = ub[(size_t)(cch * 64 + r) * NHW + (size_t)y * NW + q];
        }
        __syncthreads();
#pragma unroll
        for (int jc = 0; jc < 4; ++jc) {
            const int c = cch * 64 + eg * 4 + jc;
            const int cc = eg * 4 + jc;
            const float co0 = 0.25f * sigm_(dlog[c]);
            const float co1 = 0.25f * sigm_(dlog[NC + c]);
            const float co2 = 0.25f * sigm_(dlog[2 * NC + c]);
            const float hterm = am * hbuf[b * NC + c];
            const float b2v = b2[c];
            const float* up = ub + (size_t)c * NHW;

            float ym[6][4];
            const int dy[6] = {-1, 1, -2, 2, -4, 4};
#pragma unroll
            for (int n = 0; n < 6; ++n) {
                int ry = y + dy[n];
                ry = ry < 0 ? -ry : (ry > 63 ? 126 - ry : ry);
                const float4 t = *reinterpret_cast<const float4*>(up + (size_t)ry * NW + x0);
                ym[n][0] = t.x; ym[n][1] = t.y; ym[n][2] = t.z; ym[n][3] = t.w;
            }
            const float4 ff = *reinterpret_cast<const float4*>(frow + (size_t)c * NHW + x0);
            const float fv[4] = {ff.x, ff.y, ff.z, ff.w};
#pragma unroll
            for (int ip = 0; ip < 4; ++ip) {
                const int x = x0 + ip;
                const float uc = su[cc][x];
                int xm, xp;
                float dsum = 0.f, lap;
                xm = x - 1; xm = xm < 0 ? -xm : xm;
                xp = x + 1; xp = xp > 63 ? 126 - xp : xp;
                lap = su[cc][xm] + su[cc][xp] + ym[0][ip] + ym[1][ip] - 4.f * uc;
                dsum = fmaf(co0, lap, dsum);
                xm = x - 2; xm = xm < 0 ? -xm : xm;
                xp = x + 2; xp = xp > 63 ? 126 - xp : xp;
                lap = su[cc][xm] + su[cc][xp] + ym[2][ip] + ym[3][ip] - 4.f * uc;
                dsum = fmaf(co1, lap, dsum);
                xm = x - 4; xm = xm < 0 ? -xm : xm;
                xp = x + 4; xp = xp > 63 ? 126 - xp : xp;
                lap = su[cc][xm] + su[cc][xp] + ym[4][ip] + ym[5][ip] - 4.f * uc;
                dsum = fmaf(co2, lap, dsum);

                const float du_ = dsum + racc[cch][jc][ip] + b2v + hterm + afc * fv[ip];
                racc[cch][jc][ip] = uc + dt * du_;   // u_new
            }
        }
    }

    // ================= optional RMSNorm over channels =================
    if (do_norm) {
        float ps[4] = {0.f, 0.f, 0.f, 0.f};
#pragma unroll
        for (int a = 0; a < 4; ++a)
#pragma unroll
            for (int j = 0; j < 4; ++j)
#pragma unroll
                for (int i = 0; i < 4; ++i)
                    ps[i] = fmaf(racc[a][j][i], racc[a][j][i], ps[i]);
        __syncthreads();
        *reinterpret_cast<float4*>(&sw[eg][x0]) = make_float4(ps[0], ps[1], ps[2], ps[3]);
        __syncthreads();
        if (tid < 64) {
            float s = 0.f;
#pragma unroll
            for (int g = 0; g < 16; ++g) s += sw[g][tid];
            inv64[tid] = 1.f / (sqrtf(s) * 0.0625f + 1e-6f);  // rms = sqrt(sum)/sqrt(256)
        }
        __syncthreads();
    }

    // ================= store =================
#pragma unroll
    for (int cch = 0; cch < 4; ++cch)
#pragma unroll
        for (int jc = 0; jc < 4; ++jc) {
            const int c = cch * 64 + eg * 4 + jc;
            const float ns = do_norm ? nsc[c] : 1.f;
            float vv[4];
#pragma unroll
            for (int ip = 0; ip < 4; ++ip) {
                float v = racc[cch][jc][ip];
                if (do_norm) v *= inv64[x0 + ip] * ns;
                vv[ip] = v;
            }
            float4 o; o.x = vv[0]; o.y = vv[1]; o.z = vv[2]; o.w = vv[3];
            *reinterpret_cast<float4*>(uout + plane + (size_t)c * NHW + (size_t)y * NW + x0) = o;
        }
}

extern "C" void kernel_launch(void* const* d_in, const int* in_sizes, int n_in,
                              void* d_out, int out_size, void* d_ws, size_t ws_size,
                              hipStream_t stream) {
    (void)in_sizes; (void)n_in; (void)out_size; (void)ws_size;
    const float* u0      = (const float*)d_in[0];
    const float* forcing = (const float*)d_in[1];
    const float* dlog    = (const float*)d_in[2];
    const float* w1      = (const float*)d_in[3];
    const float* b1      = (const float*)d_in[4];
    const float* w2      = (const float*)d_in[5];
    const float* b2      = (const float*)d_in[6];
    const float* wf      = (const float*)d_in[7];
    const float* bfv     = (const float*)d_in[8];
    const float* wi      = (const float*)d_in[9];
    const float* biv     = (const float*)d_in[10];
    const float* wc      = (const float*)d_in[11];
    const float* bcv     = (const float*)d_in[12];
    const float* nsc     = (const float*)d_in[13];
    const float* p_logdt = (const float*)d_in[14];
    const float* p_am    = (const float*)d_in[15];
    const float* p_af    = (const float*)d_in[16];

    float* uout = (float*)d_out;
    float* ws   = (float*)d_ws;
    float* X0     = ws;                                  // NB*NC*NHW floats
    float* pooled = ws + (size_t)NB * NC * NHW;          // NB*NC
    float* hbuf   = pooled + NB * NC;                    // NB*NC

    const float* src = u0;
    for (int t = 0; t < STEPS; ++t) {
        float* dst = (t % 2 == 0) ? X0 : uout;           // t=5 (last) -> uout
        pool_kernel<<<NB * NC, 256, 0, stream>>>(src, pooled);
        h_kernel<<<NB, 256, 0, stream>>>(pooled, wf, bfv, wi, biv, wc, bcv, hbuf, t == 0);
        update_kernel<<<NB * NH, 256, 0, stream>>>(src, dst, forcing, dlog, w1, b1, w2, b2,
                                                   hbuf, nsc, p_logdt, p_am, p_af,
                                                   ((t + 1) % 2) == 0);
        src = dst;
    }
}

// Round 2
// 1167.441 us; speedup vs baseline: 4.4154x; 4.4154x over previous
//
#include <hip/hip_runtime.h>
#include <math.h>

constexpr int NB = 8, NC = 256, NE = 512, NH = 64, NW = 64, NHW = NH * NW;
constexpr int STEPS = 6;

typedef short bfrag8 __attribute__((ext_vector_type(8)));   // 8 bf16 in 4 VGPRs
typedef float f32x4 __attribute__((ext_vector_type(4)));

__device__ __forceinline__ float sigm_(float x) { return 1.f / (1.f + expf(-x)); }
__device__ __forceinline__ float gelu_(float x) {
    return 0.5f * x * (1.f + erff(x * 0.70710678118654752f));
}
__device__ __forceinline__ ushort f2bf(float f) {
    unsigned u = __builtin_bit_cast(unsigned, f);
    unsigned r = (u + 0x7fffu + ((u >> 16) & 1u)) >> 16;   // RNE
    return (ushort)r;
}

// ---------- prologue: bf16 transposed weights ----------
__global__ void wt_kernel(const float* __restrict__ w1, const float* __restrict__ w2,
                          ushort* __restrict__ w1t, ushort* __restrict__ w2t) {
    const int bid = blockIdx.x, tid = threadIdx.x;
    if (bid < NE) {                       // w1t[e][c] = w1[c][e]
        w1t[bid * NC + tid] = f2bf(w1[(size_t)tid * NE + bid]);
    } else {                              // w2t[c][e] = w2[e][c]
        const int c = bid - NE;
        for (int e = tid; e < NE; e += 256)
            w2t[c * NE + e] = f2bf(w2[(size_t)e * NC + c]);
    }
}

// ---------- prologue: X[m][c] bf16 from u0[b][c][hw] ----------
__global__ __launch_bounds__(256) void x0_kernel(const float* __restrict__ u,
                                                 ushort* __restrict__ X) {
    __shared__ ushort xs[64][264];
    const int tid = threadIdx.x;
    const int b = blockIdx.x >> 6, y = blockIdx.x & 63;
    const float* up = u + (size_t)b * NC * NHW + y * NW;
#pragma unroll
    for (int cc = 0; cc < 4; ++cc)
#pragma unroll
        for (int i = 0; i < 16; ++i) {
            const int idx = i * 256 + tid;
            const int c = idx >> 6, x = idx & 63;
            xs[x][cc * 64 + c] = f2bf(up[(size_t)(cc * 64 + c) * NHW + x]);
        }
    __syncthreads();
    ushort* Xp = X + ((size_t)b * NHW + y * NW) * NC;
    const int wv = tid >> 6, lane = tid & 63;
#pragma unroll
    for (int r = 0; r < 16; ++r) {
        const int row = wv * 16 + r;
        *reinterpret_cast<uint2*>(Xp + (size_t)row * NC + lane * 4) =
            *reinterpret_cast<const uint2*>(&xs[row][lane * 4]);
    }
}

// ---------- pooled = mean_{h,w} u ----------
__global__ void pool_kernel(const float* __restrict__ u, float* __restrict__ pooled) {
    const int bc = blockIdx.x;
    const float* base = u + (size_t)bc * NHW;
    const int tid = threadIdx.x;
    float s = 0.f;
#pragma unroll
    for (int i = 0; i < 4; ++i) {
        const float4 v = *reinterpret_cast<const float4*>(base + i * 1024 + tid * 4);
        s += v.x + v.y + v.z + v.w;
    }
#pragma unroll
    for (int off = 32; off > 0; off >>= 1) s += __shfl_down(s, off, 64);
    __shared__ float red[4];
    if ((tid & 63) == 0) red[tid >> 6] = s;
    __syncthreads();
    if (tid == 0) pooled[bc] = (red[0] + red[1] + red[2] + red[3]) * (1.f / NHW);
}

// ---------- gated global memory state ----------
__global__ void h_kernel(const float* __restrict__ pooled,
                         const float* __restrict__ wf, const float* __restrict__ bfv,
                         const float* __restrict__ wi, const float* __restrict__ biv,
                         const float* __restrict__ wc, const float* __restrict__ bcv,
                         float* __restrict__ h, const int first) {
    const int b = blockIdx.x;
    const int c = threadIdx.x;
    __shared__ float sp[NC];
    sp[c] = pooled[b * NC + c];
    __syncthreads();
    float af = bfv[c], ai = biv[c], ac = bcv[c];
    for (int k = 0; k < NC; ++k) {
        const float p = sp[k];
        af = fmaf(p, wf[k * NC + c], af);
        ai = fmaf(p, wi[k * NC + c], ai);
        ac = fmaf(p, wc[k * NC + c], ac);
    }
    const float f  = sigm_(af);
    const float ii = sigm_(ai);
    const float cc = tanhf(ac);
    const float hold = first ? 0.f : h[b * NC + c];
    h[b * NC + c] = hold * f + ii * cc;
}

// ---------- GEMM1: H1[m][e] = gelu(X[m][:] @ w1 + b1), bf16 MFMA ----------
__global__ __launch_bounds__(256, 2) void gemm1_kernel(
    const ushort* __restrict__ X, const ushort* __restrict__ w1t,
    const float* __restrict__ b1, ushort* __restrict__ H1) {
    const int tid = threadIdx.x;
    const int wv = tid >> 6, lane = tid & 63;
    const int etile = blockIdx.x & 3, mtile = blockIdx.x >> 2;
    const int m0 = mtile * 64 + wv * 16;
    const int e0 = etile * 128;
    const int r16 = lane & 15, kg = lane >> 4;

    const ushort* xp = X + (size_t)(m0 + r16) * NC + kg * 8;
    const ushort* wp = w1t + (size_t)(e0 + r16) * NC + kg * 8;

    f32x4 acc[8];
#pragma unroll
    for (int f = 0; f < 8; ++f) acc[f] = (f32x4){0.f, 0.f, 0.f, 0.f};

#pragma unroll
    for (int ks = 0; ks < 8; ++ks) {
        const bfrag8 a = *reinterpret_cast<const bfrag8*>(xp + ks * 32);
#pragma unroll
        for (int f = 0; f < 8; ++f) {
            const bfrag8 bb = *reinterpret_cast<const bfrag8*>(wp + (size_t)f * 16 * NC + ks * 32);
            acc[f] = __builtin_amdgcn_mfma_f32_16x16x32_bf16(a, bb, acc[f], 0, 0, 0);
        }
    }
    // D: col=lane&15 (e), row=(lane>>4)*4+j (m)
#pragma unroll
    for (int f = 0; f < 8; ++f) {
        const int e = e0 + f * 16 + r16;
        const float bb1 = b1[e];
#pragma unroll
        for (int j = 0; j < 4; ++j) {
            const float v = gelu_(acc[f][j] + bb1);
            H1[(size_t)(m0 + kg * 4 + j) * NE + e] = f2bf(v);
        }
    }
}

// ---------- GEMM2 (bf16 MFMA) fused with stencil + memory + Euler + RMSNorm ----------
__global__ __launch_bounds__(256, 2) void gemm2_update_kernel(
    const ushort* __restrict__ H1, const ushort* __restrict__ w2t,
    const float* __restrict__ b2, const float* __restrict__ uin,
    const float* __restrict__ forcing, const float* __restrict__ dlog,
    const float* __restrict__ hbuf, const float* __restrict__ nsc,
    const float* __restrict__ p_logdt, const float* __restrict__ p_am,
    const float* __restrict__ p_af, const int do_norm,
    float* __restrict__ uout, ushort* __restrict__ Xout) {
    __shared__ __align__(16) char pool[64 * 68 * 4 * 2];          // tr + su (overlaid by xs)
    float (*tr)[68] = (float (*)[68])pool;                         // react tile [c'][px]
    float (*su)[68] = (float (*)[68])(pool + 64 * 68 * 4);         // u_old tile [c'][px]
    ushort (*xs)[264] = (ushort (*)[264])pool;                     // bf16 out [px][c]
    __shared__ float redc[16][68];
    __shared__ float inv64[64];

    const int tid = threadIdx.x;
    const int wv = tid >> 6, lane = tid & 63;
    const int b = blockIdx.x >> 6, y = blockIdx.x & 63;
    const int r16 = lane & 15, kg = lane >> 4;

    // ---- GEMM phase: out tile [64 px x 256 c], K=512 ----
    const size_t m0 = (size_t)b * NHW + (size_t)y * NW + wv * 16;
    const ushort* hp = H1 + (m0 + r16) * NE + kg * 8;
    const ushort* wp = w2t + (size_t)r16 * NE + kg * 8;

    f32x4 acc[16];
#pragma unroll
    for (int f = 0; f < 16; ++f) acc[f] = (f32x4){0.f, 0.f, 0.f, 0.f};

    for (int ks = 0; ks < 16; ++ks) {
        const bfrag8 a = *reinterpret_cast<const bfrag8*>(hp + ks * 32);
#pragma unroll
        for (int f = 0; f < 16; ++f) {
            const bfrag8 bb = *reinterpret_cast<const bfrag8*>(wp + (size_t)f * 16 * NE + ks * 32);
            acc[f] = __builtin_amdgcn_mfma_f32_16x16x32_bf16(a, bb, acc[f], 0, 0, 0);
        }
    }

    // ---- epilogue ----
    const int eg = tid >> 4, pg = tid & 15, x0 = pg * 4;
    const float dt = fminf(fmaxf(expf(p_logdt[0]), 0.01f), 0.3f);
    const float am = p_am[0], afc = p_af[0];
    const float* ub = uin + (size_t)b * NC * NHW;
    const float* frow = forcing + (size_t)b * NC * NHW + (size_t)y * NW;

    float unew[4][4][4];   // [ch][jc][ip]

#pragma unroll
    for (int ch = 0; ch < 4; ++ch) {
        __syncthreads();
        // transpose react frags (D layout) into tr[c'][px]
#pragma unroll
        for (int f2 = 0; f2 < 4; ++f2) {
            const int cpr = f2 * 16 + r16;
            const int pxb = wv * 16 + kg * 4;
#pragma unroll
            for (int j = 0; j < 4; ++j)
                tr[cpr][pxb + j] = acc[ch * 4 + f2][j];
        }
        // stage u_old chunk [64 c][64 px]
#pragma unroll
        for (int i = 0; i < 16; ++i) {
            const int idx = i * 256 + tid;
            const int r = idx >> 6, q = idx & 63;
            su[r][q] = ub[(size_t)(ch * 64 + r) * NHW + (size_t)y * NW + q];
        }
        __syncthreads();

#pragma unroll
        for (int jc = 0; jc < 4; ++jc) {
            const int cc = eg * 4 + jc;
            const int c = ch * 64 + cc;
            const float co0 = 0.25f * sigm_(dlog[c]);
            const float co1 = 0.25f * sigm_(dlog[NC + c]);
            const float co2 = 0.25f * sigm_(dlog[2 * NC + c]);
            const float hterm = am * hbuf[b * NC + c];
            const float b2v = b2[c];
            const float* up = ub + (size_t)c * NHW;

            float ym[6][4];
            const int dy[6] = {-1, 1, -2, 2, -4, 4};
#pragma unroll
            for (int n = 0; n < 6; ++n) {
                int ry = y + dy[n];
                ry = ry < 0 ? -ry : (ry > 63 ? 126 - ry : ry);
                const float4 t = *reinterpret_cast<const float4*>(up + (size_t)ry * NW + x0);
                ym[n][0] = t.x; ym[n][1] = t.y; ym[n][2] = t.z; ym[n][3] = t.w;
            }
            const float4 ff = *reinterpret_cast<const float4*>(frow + (size_t)c * NHW + x0);
            const float fv[4] = {ff.x, ff.y, ff.z, ff.w};
            const f32x4 rv = *reinterpret_cast<const f32x4*>(&tr[cc][x0]);
#pragma unroll
            for (int ip = 0; ip < 4; ++ip) {
                const int x = x0 + ip;
                const float uc = su[cc][x];
                int xm, xp2;
                float dsum = 0.f, lap;
                xm = x - 1; xm = xm < 0 ? -xm : xm;
                xp2 = x + 1; xp2 = xp2 > 63 ? 126 - xp2 : xp2;
                lap = su[cc][xm] + su[cc][xp2] + ym[0][ip] + ym[1][ip] - 4.f * uc;
                dsum = fmaf(co0, lap, dsum);
                xm = x - 2; xm = xm < 0 ? -xm : xm;
                xp2 = x + 2; xp2 = xp2 > 63 ? 126 - xp2 : xp2;
                lap = su[cc][xm] + su[cc][xp2] + ym[2][ip] + ym[3][ip] - 4.f * uc;
                dsum = fmaf(co1, lap, dsum);
                xm = x - 4; xm = xm < 0 ? -xm : xm;
                xp2 = x + 4; xp2 = xp2 > 63 ? 126 - xp2 : xp2;
                lap = su[cc][xm] + su[cc][xp2] + ym[4][ip] + ym[5][ip] - 4.f * uc;
                dsum = fmaf(co2, lap, dsum);

                const float du_ = dsum + rv[ip] + b2v + hterm + afc * fv[ip];
                unew[ch][jc][ip] = uc + dt * du_;
            }
        }
    }

    // ---- RMSNorm over channels ----
    if (do_norm) {
        float ps[4] = {0.f, 0.f, 0.f, 0.f};
#pragma unroll
        for (int ch = 0; ch < 4; ++ch)
#pragma unroll
            for (int jc = 0; jc < 4; ++jc)
#pragma unroll
                for (int ip = 0; ip < 4; ++ip)
                    ps[ip] = fmaf(unew[ch][jc][ip], unew[ch][jc][ip], ps[ip]);
        __syncthreads();
        *reinterpret_cast<f32x4*>(&redc[eg][x0]) = (f32x4){ps[0], ps[1], ps[2], ps[3]};
        __syncthreads();
        if (tid < 64) {
            float s = 0.f;
#pragma unroll
            for (int g = 0; g < 16; ++g) s += redc[g][tid];
            inv64[tid] = 1.f / (sqrtf(s) * 0.0625f + 1e-6f);
        }
        __syncthreads();
    }

    // ---- store u_new (fp32, channel-major) + stage bf16 X (pixel-major) ----
    __syncthreads();   // tr/su fully consumed; pool reused as xs
    float* uob = uout + (size_t)b * NC * NHW + (size_t)y * NW;
#pragma unroll
    for (int ch = 0; ch < 4; ++ch)
#pragma unroll
        for (int jc = 0; jc < 4; ++jc) {
            const int cc = eg * 4 + jc;
            const int c = ch * 64 + cc;
            const float ns = do_norm ? nsc[c] : 1.f;
            float vv[4];
#pragma unroll
            for (int ip = 0; ip < 4; ++ip) {
                float v = unew[ch][jc][ip];
                if (do_norm) v *= inv64[x0 + ip] * ns;
                vv[ip] = v;
                xs[x0 + ip][c] = f2bf(v);
            }
            float4 o; o.x = vv[0]; o.y = vv[1]; o.z = vv[2]; o.w = vv[3];
            *reinterpret_cast<float4*>(uob + (size_t)c * NHW + x0) = o;
        }
    __syncthreads();
    ushort* Xp = Xout + ((size_t)b * NHW + (size_t)y * NW) * NC;
#pragma unroll
    for (int r = 0; r < 16; ++r) {
        const int row = wv * 16 + r;
        *reinterpret_cast<uint2*>(Xp + (size_t)row * NC + lane * 4) =
            *reinterpret_cast<const uint2*>(&xs[row][lane * 4]);
    }
}

extern "C" void kernel_launch(void* const* d_in, const int* in_sizes, int n_in,
                              void* d_out, int out_size, void* d_ws, size_t ws_size,
                              hipStream_t stream) {
    (void)in_sizes; (void)n_in; (void)out_size; (void)ws_size;
    const float* u0      = (const float*)d_in[0];
    const float* forcing = (const float*)d_in[1];
    const float* dlog    = (const float*)d_in[2];
    const float* w1      = (const float*)d_in[3];
    const float* b1      = (const float*)d_in[4];
    const float* w2      = (const float*)d_in[5];
    const float* b2      = (const float*)d_in[6];
    const float* wf      = (const float*)d_in[7];
    const float* bfv     = (const float*)d_in[8];
    const float* wi      = (const float*)d_in[9];
    const float* biv     = (const float*)d_in[10];
    const float* wc      = (const float*)d_in[11];
    const float* bcv     = (const float*)d_in[12];
    const float* nsc     = (const float*)d_in[13];
    const float* p_logdt = (const float*)d_in[14];
    const float* p_am    = (const float*)d_in[15];
    const float* p_af    = (const float*)d_in[16];

    float* uout = (float*)d_out;

    char* w = (char*)d_ws;
    float*  uA   = (float*)w;   w += (size_t)NB * NC * NHW * 4;   // 33.5 MB
    ushort* X    = (ushort*)w;  w += (size_t)NB * NHW * NC * 2;   // 16.8 MB
    ushort* H1   = (ushort*)w;  w += (size_t)NB * NHW * NE * 2;   // 33.5 MB
    ushort* w1t  = (ushort*)w;  w += (size_t)NE * NC * 2;
    ushort* w2t  = (ushort*)w;  w += (size_t)NC * NE * 2;
    float* pooled = (float*)w;  w += (size_t)NB * NC * 4;
    float* hbuf   = (float*)w;  w += (size_t)NB * NC * 4;

    wt_kernel<<<768, 256, 0, stream>>>(w1, w2, w1t, w2t);
    x0_kernel<<<NB * NH, 256, 0, stream>>>(u0, X);

    const float* src = u0;
    for (int t = 0; t < STEPS; ++t) {
        float* dst = (t & 1) ? uout : uA;    // t=5 -> uout
        pool_kernel<<<NB * NC, 256, 0, stream>>>(src, pooled);
        h_kernel<<<NB, 256, 0, stream>>>(pooled, wf, bfv, wi, biv, wc, bcv, hbuf, t == 0);
        gemm1_kernel<<<2048, 256, 0, stream>>>(X, w1t, b1, H1);
        gemm2_update_kernel<<<NB * NH, 256, 0, stream>>>(H1, w2t, b2, src, forcing, dlog,
                                                         hbuf, nsc, p_logdt, p_am, p_af,
                                                         ((t + 1) % 2) == 0, dst, X);
        src = dst;
    }
}

// Round 3
// 777.303 us; speedup vs baseline: 6.6315x; 1.5019x over previous
//
#include <hip/hip_runtime.h>
#include <math.h>

constexpr int NB = 8, NC = 256, NE = 512, NH = 64, NW = 64, NHW = NH * NW;
constexpr int STEPS = 6;

typedef short bfrag8 __attribute__((ext_vector_type(8)));   // 8 bf16 in 4 VGPRs
typedef float f32x4 __attribute__((ext_vector_type(4)));

__device__ __forceinline__ float sigm_(float x) { return 1.f / (1.f + expf(-x)); }
__device__ __forceinline__ float gelu_(float x) {
    return 0.5f * x * (1.f + erff(x * 0.70710678118654752f));
}
__device__ __forceinline__ ushort f2bf(float f) {
    unsigned u = __builtin_bit_cast(unsigned, f);
    unsigned r = (u + 0x7fffu + ((u >> 16) & 1u)) >> 16;   // RNE
    return (ushort)r;
}
__device__ __forceinline__ void gload16(const void* g, void* l) {
    __builtin_amdgcn_global_load_lds((const __attribute__((address_space(1))) void*)g,
                                     (__attribute__((address_space(3))) void*)l, 16, 0, 0);
}

// ---------- prologue: bf16 transposed weights ----------
__global__ void wt_kernel(const float* __restrict__ w1, const float* __restrict__ w2,
                          ushort* __restrict__ w1t, ushort* __restrict__ w2t) {
    const int bid = blockIdx.x, tid = threadIdx.x;
    if (bid < NE) {                       // w1t[e][c] = w1[c][e]
        w1t[bid * NC + tid] = f2bf(w1[(size_t)tid * NE + bid]);
    } else {                              // w2t[c][e] = w2[e][c]
        const int c = bid - NE;
        for (int e = tid; e < NE; e += 256)
            w2t[c * NE + e] = f2bf(w2[(size_t)e * NC + c]);
    }
}

// ---------- prologue: X[m][c] bf16 from u0[b][c][hw] ----------
__global__ __launch_bounds__(256) void x0_kernel(const float* __restrict__ u,
                                                 ushort* __restrict__ X) {
    __shared__ ushort xs[64][264];
    const int tid = threadIdx.x;
    const int b = blockIdx.x >> 6, y = blockIdx.x & 63;
    const float* up = u + (size_t)b * NC * NHW + y * NW;
#pragma unroll
    for (int cc = 0; cc < 4; ++cc)
#pragma unroll
        for (int i = 0; i < 16; ++i) {
            const int idx = i * 256 + tid;
            const int c = idx >> 6, x = idx & 63;
            xs[x][cc * 64 + c] = f2bf(up[(size_t)(cc * 64 + c) * NHW + x]);
        }
    __syncthreads();
    ushort* Xp = X + ((size_t)b * NHW + y * NW) * NC;
    const int wv = tid >> 6, lane = tid & 63;
#pragma unroll
    for (int r = 0; r < 16; ++r) {
        const int row = wv * 16 + r;
        *reinterpret_cast<uint2*>(Xp + (size_t)row * NC + lane * 4) =
            *reinterpret_cast<const uint2*>(&xs[row][lane * 4]);
    }
}

// ---------- pooled = mean_{h,w} u ----------
__global__ void pool_kernel(const float* __restrict__ u, float* __restrict__ pooled) {
    const int bc = blockIdx.x;
    const float* base = u + (size_t)bc * NHW;
    const int tid = threadIdx.x;
    float s = 0.f;
#pragma unroll
    for (int i = 0; i < 4; ++i) {
        const float4 v = *reinterpret_cast<const float4*>(base + i * 1024 + tid * 4);
        s += v.x + v.y + v.z + v.w;
    }
#pragma unroll
    for (int off = 32; off > 0; off >>= 1) s += __shfl_down(s, off, 64);
    __shared__ float red[4];
    if ((tid & 63) == 0) red[tid >> 6] = s;
    __syncthreads();
    if (tid == 0) pooled[bc] = (red[0] + red[1] + red[2] + red[3]) * (1.f / NHW);
}

// ---------- gated global memory state ----------
__global__ void h_kernel(const float* __restrict__ pooled,
                         const float* __restrict__ wf, const float* __restrict__ bfv,
                         const float* __restrict__ wi, const float* __restrict__ biv,
                         const float* __restrict__ wc, const float* __restrict__ bcv,
                         float* __restrict__ h, const int first) {
    const int b = blockIdx.x;
    const int c = threadIdx.x;
    __shared__ float sp[NC];
    sp[c] = pooled[b * NC + c];
    __syncthreads();
    float af = bfv[c], ai = biv[c], ac = bcv[c];
    for (int k = 0; k < NC; ++k) {
        const float p = sp[k];
        af = fmaf(p, wf[k * NC + c], af);
        ai = fmaf(p, wi[k * NC + c], ai);
        ac = fmaf(p, wc[k * NC + c], ac);
    }
    const float f  = sigm_(af);
    const float ii = sigm_(ai);
    const float cc = tanhf(ac);
    const float hold = first ? 0.f : h[b * NC + c];
    h[b * NC + c] = hold * f + ii * cc;
}

// ---------- GEMM1: H1 = gelu(X @ w1 + b1), 128x128 tile, LDS dbuf ----------
__global__ __launch_bounds__(256, 2) void gemm1_kernel(
    const ushort* __restrict__ X, const ushort* __restrict__ w1t,
    const float* __restrict__ b1, ushort* __restrict__ H1) {
    __shared__ __align__(16) char pool[65536];   // 2 x (As 16KB + Bs 16KB)
    const int tid = threadIdx.x;
    const int wv = tid >> 6, lane = tid & 63;
    const int r16 = lane & 15, kg = lane >> 4;
    const int wvm = wv & 1, wvn = wv >> 1;
    const int m0 = (blockIdx.x >> 2) * 128, e0 = (blockIdx.x & 3) * 128;

    f32x4 acc[4][4];
#pragma unroll
    for (int mi = 0; mi < 4; ++mi)
#pragma unroll
        for (int ni = 0; ni < 4; ++ni) acc[mi][ni] = (f32x4){0.f, 0.f, 0.f, 0.f};

    auto stage = [&](int buf, int kc) {
        ushort* As = (ushort*)(pool + buf * 32768);   // [128][64]
        ushort* Bs = As + 8192;                       // [128][64]
#pragma unroll
        for (int i = 0; i < 4; ++i) {
            const int idx = i * 256 + tid;
            const int row = idx >> 3, s = idx & 7;
            const int cs = kc * 64 + ((s ^ (row & 7)) << 3);   // inverse-swz source
            gload16(X + (size_t)(m0 + row) * NC + cs, As + idx * 8);
            gload16(w1t + (size_t)(e0 + row) * NC + cs, Bs + idx * 8);
        }
    };

    stage(0, 0);
    for (int kc = 0; kc < 4; ++kc) {
        __syncthreads();                      // buf(kc) loads complete
        if (kc < 3) stage((kc + 1) & 1, kc + 1);
        const ushort* As = (const ushort*)(pool + (kc & 1) * 32768);
        const ushort* Bs = As + 8192;
#pragma unroll
        for (int ks = 0; ks < 2; ++ks) {
            bfrag8 av[4], bv[4];
#pragma unroll
            for (int mi = 0; mi < 4; ++mi) {
                const int row = wvm * 64 + mi * 16 + r16;
                av[mi] = *(const bfrag8*)(As + row * 64 + (((ks * 4 + kg) ^ (row & 7)) << 3));
            }
#pragma unroll
            for (int ni = 0; ni < 4; ++ni) {
                const int row = wvn * 64 + ni * 16 + r16;
                bv[ni] = *(const bfrag8*)(Bs + row * 64 + (((ks * 4 + kg) ^ (row & 7)) << 3));
            }
#pragma unroll
            for (int mi = 0; mi < 4; ++mi)
#pragma unroll
                for (int ni = 0; ni < 4; ++ni)
                    acc[mi][ni] = __builtin_amdgcn_mfma_f32_16x16x32_bf16(av[mi], bv[ni],
                                                                          acc[mi][ni], 0, 0, 0);
        }
    }

    // epilogue: gelu -> LDS transpose -> coalesced dwordx4 stores
    __syncthreads();
    ushort* Hs = (ushort*)pool;   // [128][128]
    float bb[4];
#pragma unroll
    for (int ni = 0; ni < 4; ++ni) bb[ni] = b1[e0 + wvn * 64 + ni * 16 + r16];
#pragma unroll
    for (int mi = 0; mi < 4; ++mi)
#pragma unroll
        for (int ni = 0; ni < 4; ++ni)
#pragma unroll
            for (int j = 0; j < 4; ++j)
                Hs[(wvm * 64 + mi * 16 + kg * 4 + j) * 128 + wvn * 64 + ni * 16 + r16] =
                    f2bf(gelu_(acc[mi][ni][j] + bb[ni]));
    __syncthreads();
#pragma unroll
    for (int i = 0; i < 8; ++i) {
        const int idx = i * 256 + tid;
        const int row = idx >> 4, s = idx & 15;
        *reinterpret_cast<uint4*>(H1 + (size_t)(m0 + row) * NE + e0 + s * 8) =
            *reinterpret_cast<const uint4*>(Hs + row * 128 + s * 8);
    }
}

// ---------- GEMM2 (64px x 256c, K=512, LDS dbuf) + stencil/memory/Euler/RMSNorm ----------
__global__ __launch_bounds__(256, 2) void gemm2_update_kernel(
    const ushort* __restrict__ H1, const ushort* __restrict__ w2t,
    const float* __restrict__ b2, const float* __restrict__ uin,
    const float* __restrict__ forcing, const float* __restrict__ dlog,
    const float* __restrict__ hbuf, const float* __restrict__ nsc,
    const float* __restrict__ p_logdt, const float* __restrict__ p_am,
    const float* __restrict__ p_af, const int do_norm,
    float* __restrict__ uout, ushort* __restrict__ Xout) {
    __shared__ __align__(16) char pool[81920];   // 2 x (As 8KB + Bs 32KB); epilogue overlays
    const int tid = threadIdx.x;
    const int wv = tid >> 6, lane = tid & 63;
    const int r16 = lane & 15, kg = lane >> 4;
    const int b = blockIdx.x >> 6, y = blockIdx.x & 63;
    const int m0 = blockIdx.x * 64;

    f32x4 acc[4][4];   // [mi px][ni c]; wave's c-slice = wv*64
#pragma unroll
    for (int mi = 0; mi < 4; ++mi)
#pragma unroll
        for (int ni = 0; ni < 4; ++ni) acc[mi][ni] = (f32x4){0.f, 0.f, 0.f, 0.f};

    auto stage = [&](int buf, int kc) {
        ushort* As = (ushort*)(pool + buf * 40960);   // [64][64]
        ushort* Bs = As + 4096;                       // [256][64]
#pragma unroll
        for (int i = 0; i < 2; ++i) {
            const int idx = i * 256 + tid;
            const int row = idx >> 3, s = idx & 7;
            gload16(H1 + (size_t)(m0 + row) * NE + kc * 64 + ((s ^ (row & 7)) << 3),
                    As + idx * 8);
        }
#pragma unroll
        for (int i = 0; i < 8; ++i) {
            const int idx = i * 256 + tid;
            const int row = idx >> 3, s = idx & 7;
            gload16(w2t + (size_t)row * NE + kc * 64 + ((s ^ (row & 7)) << 3),
                    Bs + idx * 8);
        }
    };

    stage(0, 0);
    for (int kc = 0; kc < 8; ++kc) {
        __syncthreads();
        if (kc < 7) stage((kc + 1) & 1, kc + 1);
        const ushort* As = (const ushort*)(pool + (kc & 1) * 40960);
        const ushort* Bs = As + 4096;
#pragma unroll
        for (int ks = 0; ks < 2; ++ks) {
            bfrag8 av[4], bv[4];
#pragma unroll
            for (int mi = 0; mi < 4; ++mi) {
                const int row = mi * 16 + r16;
                av[mi] = *(const bfrag8*)(As + row * 64 + (((ks * 4 + kg) ^ (row & 7)) << 3));
            }
#pragma unroll
            for (int ni = 0; ni < 4; ++ni) {
                const int row = wv * 64 + ni * 16 + r16;
                bv[ni] = *(const bfrag8*)(Bs + row * 64 + (((ks * 4 + kg) ^ (row & 7)) << 3));
            }
#pragma unroll
            for (int mi = 0; mi < 4; ++mi)
#pragma unroll
                for (int ni = 0; ni < 4; ++ni)
                    acc[mi][ni] = __builtin_amdgcn_mfma_f32_16x16x32_bf16(av[mi], bv[ni],
                                                                          acc[mi][ni], 0, 0, 0);
        }
    }

    // ---- epilogue: two halves; waves dump acc -> trh, all threads run stencil ----
    float* trh = (float*)pool;                     // [128][68] f32
    float* su  = (float*)(pool + 34816);           // [64][68] f32
    const int eg = tid >> 4, pg = tid & 15, x0p = pg * 4;
    const float dt = fminf(fmaxf(expf(p_logdt[0]), 0.01f), 0.3f);
    const float am = p_am[0], afc = p_af[0];
    const float* ub = uin + (size_t)b * NC * NHW;
    const float* frow = forcing + (size_t)b * NC * NHW + (size_t)y * NW;

    float unew[4][4][4];   // [ch][jc][ip]

#pragma unroll
    for (int h2 = 0; h2 < 2; ++h2) {
        __syncthreads();                 // protect trh region (GEMM bufs / prev half)
        if ((wv >> 1) == h2) {
#pragma unroll
            for (int mi = 0; mi < 4; ++mi)
#pragma unroll
                for (int ni = 0; ni < 4; ++ni)
#pragma unroll
                    for (int j = 0; j < 4; ++j)
                        trh[((wv & 1) * 64 + ni * 16 + r16) * 68 + mi * 16 + kg * 4 + j] =
                            acc[mi][ni][j];
        }
#pragma unroll
        for (int chi = 0; chi < 2; ++chi) {
            const int ch = h2 * 2 + chi;
            __syncthreads();             // trh ready / prev su reads done
#pragma unroll
            for (int i = 0; i < 16; ++i) {
                const int idx = i * 256 + tid;
                const int r = idx >> 6, q = idx & 63;
                su[r * 68 + q] = ub[(size_t)(ch * 64 + r) * NHW + (size_t)y * NW + q];
            }
            __syncthreads();
#pragma unroll
            for (int jc = 0; jc < 4; ++jc) {
                const int cc = eg * 4 + jc;
                const int c = ch * 64 + cc;
                const float co0 = 0.25f * sigm_(dlog[c]);
                const float co1 = 0.25f * sigm_(dlog[NC + c]);
                const float co2 = 0.25f * sigm_(dlog[2 * NC + c]);
                const float hterm = am * hbuf[b * NC + c];
                const float b2v = b2[c];
                const float* up = ub + (size_t)c * NHW;

                float ym[6][4];
                const int dy[6] = {-1, 1, -2, 2, -4, 4};
#pragma unroll
                for (int n = 0; n < 6; ++n) {
                    int ry = y + dy[n];
                    ry = ry < 0 ? -ry : (ry > 63 ? 126 - ry : ry);
                    const float4 t = *reinterpret_cast<const float4*>(up + (size_t)ry * NW + x0p);
                    ym[n][0] = t.x; ym[n][1] = t.y; ym[n][2] = t.z; ym[n][3] = t.w;
                }
                const float4 ff = *reinterpret_cast<const float4*>(frow + (size_t)c * NHW + x0p);
                const float fv[4] = {ff.x, ff.y, ff.z, ff.w};
                const f32x4 rv = *reinterpret_cast<const f32x4*>(&trh[(chi * 64 + cc) * 68 + x0p]);
#pragma unroll
                for (int ip = 0; ip < 4; ++ip) {
                    const int x = x0p + ip;
                    const float uc = su[cc * 68 + x];
                    int xm, xp2;
                    float dsum = 0.f, lap;
                    xm = x - 1; xm = xm < 0 ? -xm : xm;
                    xp2 = x + 1; xp2 = xp2 > 63 ? 126 - xp2 : xp2;
                    lap = su[cc * 68 + xm] + su[cc * 68 + xp2] + ym[0][ip] + ym[1][ip] - 4.f * uc;
                    dsum = fmaf(co0, lap, dsum);
                    xm = x - 2; xm = xm < 0 ? -xm : xm;
                    xp2 = x + 2; xp2 = xp2 > 63 ? 126 - xp2 : xp2;
                    lap = su[cc * 68 + xm] + su[cc * 68 + xp2] + ym[2][ip] + ym[3][ip] - 4.f * uc;
                    dsum = fmaf(co1, lap, dsum);
                    xm = x - 4; xm = xm < 0 ? -xm : xm;
                    xp2 = x + 4; xp2 = xp2 > 63 ? 126 - xp2 : xp2;
                    lap = su[cc * 68 + xm] + su[cc * 68 + xp2] + ym[4][ip] + ym[5][ip] - 4.f * uc;
                    dsum = fmaf(co2, lap, dsum);

                    const float du_ = dsum + rv[ip] + b2v + hterm + afc * fv[ip];
                    unew[ch][jc][ip] = uc + dt * du_;
                }
            }
        }
    }

    // ---- RMSNorm over channels ----
    float* redc = (float*)(pool + 34816);          // [16][68] (overlays su)
    float* inv64p = (float*)(pool + 39168);        // [64]
    if (do_norm) {
        float ps[4] = {0.f, 0.f, 0.f, 0.f};
#pragma unroll
        for (int ch = 0; ch < 4; ++ch)
#pragma unroll
            for (int jc = 0; jc < 4; ++jc)
#pragma unroll
                for (int ip = 0; ip < 4; ++ip)
                    ps[ip] = fmaf(unew[ch][jc][ip], unew[ch][jc][ip], ps[ip]);
        __syncthreads();
        *reinterpret_cast<f32x4*>(&redc[eg * 68 + x0p]) = (f32x4){ps[0], ps[1], ps[2], ps[3]};
        __syncthreads();
        if (tid < 64) {
            float s = 0.f;
#pragma unroll
            for (int g = 0; g < 16; ++g) s += redc[g * 68 + tid];
            inv64p[tid] = 1.f / (sqrtf(s) * 0.0625f + 1e-6f);
        }
    }
    __syncthreads();   // trh reads done; inv64p ready; reuse pool front as xs

    // ---- store u_new (fp32) + bf16 X (pixel-major) ----
    ushort* xs = (ushort*)pool;   // [64][264]
    float* uob = uout + (size_t)b * NC * NHW + (size_t)y * NW;
#pragma unroll
    for (int ch = 0; ch < 4; ++ch)
#pragma unroll
        for (int jc = 0; jc < 4; ++jc) {
            const int cc = eg * 4 + jc;
            const int c = ch * 64 + cc;
            const float ns = do_norm ? nsc[c] : 1.f;
            float vv[4];
#pragma unroll
            for (int ip = 0; ip < 4; ++ip) {
                float v = unew[ch][jc][ip];
                if (do_norm) v *= inv64p[x0p + ip] * ns;
                vv[ip] = v;
                xs[(x0p + ip) * 264 + c] = f2bf(v);
            }
            float4 o; o.x = vv[0]; o.y = vv[1]; o.z = vv[2]; o.w = vv[3];
            *reinterpret_cast<float4*>(uob + (size_t)c * NHW + x0p) = o;
        }
    __syncthreads();
    ushort* Xp = Xout + (size_t)m0 * NC;
#pragma unroll
    for (int r = 0; r < 16; ++r) {
        const int row = wv * 16 + r;
        *reinterpret_cast<uint2*>(Xp + (size_t)row * NC + lane * 4) =
            *reinterpret_cast<const uint2*>(&xs[row * 264 + lane * 4]);
    }
}

extern "C" void kernel_launch(void* const* d_in, const int* in_sizes, int n_in,
                              void* d_out, int out_size, void* d_ws, size_t ws_size,
                              hipStream_t stream) {
    (void)in_sizes; (void)n_in; (void)out_size; (void)ws_size;
    const float* u0      = (const float*)d_in[0];
    const float* forcing = (const float*)d_in[1];
    const float* dlog    = (const float*)d_in[2];
    const float* w1      = (const float*)d_in[3];
    const float* b1      = (const float*)d_in[4];
    const float* w2      = (const float*)d_in[5];
    const float* b2      = (const float*)d_in[6];
    const float* wf      = (const float*)d_in[7];
    const float* bfv     = (const float*)d_in[8];
    const float* wi      = (const float*)d_in[9];
    const float* biv     = (const float*)d_in[10];
    const float* wc      = (const float*)d_in[11];
    const float* bcv     = (const float*)d_in[12];
    const float* nsc     = (const float*)d_in[13];
    const float* p_logdt = (const float*)d_in[14];
    const float* p_am    = (const float*)d_in[15];
    const float* p_af    = (const float*)d_in[16];

    float* uout = (float*)d_out;

    char* w = (char*)d_ws;
    float*  uA   = (float*)w;   w += (size_t)NB * NC * NHW * 4;   // 33.5 MB
    ushort* X    = (ushort*)w;  w += (size_t)NB * NHW * NC * 2;   // 16.8 MB
    ushort* H1   = (ushort*)w;  w += (size_t)NB * NHW * NE * 2;   // 33.5 MB
    ushort* w1t  = (ushort*)w;  w += (size_t)NE * NC * 2;
    ushort* w2t  = (ushort*)w;  w += (size_t)NC * NE * 2;
    float* pooled = (float*)w;  w += (size_t)NB * NC * 4;
    float* hbuf   = (float*)w;  w += (size_t)NB * NC * 4;

    wt_kernel<<<768, 256, 0, stream>>>(w1, w2, w1t, w2t);
    x0_kernel<<<NB * NH, 256, 0, stream>>>(u0, X);

    const float* src = u0;
    for (int t = 0; t < STEPS; ++t) {
        float* dst = (t & 1) ? uout : uA;    // t=5 -> uout
        pool_kernel<<<NB * NC, 256, 0, stream>>>(src, pooled);
        h_kernel<<<NB, 256, 0, stream>>>(pooled, wf, bfv, wi, biv, wc, bcv, hbuf, t == 0);
        gemm1_kernel<<<1024, 256, 0, stream>>>(X, w1t, b1, H1);
        gemm2_update_kernel<<<NB * NH, 256, 0, stream>>>(H1, w2t, b2, src, forcing, dlog,
                                                         hbuf, nsc, p_logdt, p_am, p_af,
                                                         ((t + 1) % 2) == 0, dst, X);
        src = dst;
    }
}

// Round 4
// 624.925 us; speedup vs baseline: 8.2485x; 1.2438x over previous
//
#include <hip/hip_runtime.h>
#include <math.h>

constexpr int NB = 8, NC = 256, NE = 512, NH = 64, NW = 64, NHW = NH * NW;
constexpr int STEPS = 6;

typedef short bfrag8 __attribute__((ext_vector_type(8)));   // 8 bf16 in 4 VGPRs
typedef float f32x4 __attribute__((ext_vector_type(4)));

__device__ __forceinline__ float sigm_(float x) { return 1.f / (1.f + expf(-x)); }
__device__ __forceinline__ float gelu_(float x) {
    return 0.5f * x * (1.f + erff(x * 0.70710678118654752f));
}
__device__ __forceinline__ ushort f2bf(float f) {
    unsigned u = __builtin_bit_cast(unsigned, f);
    unsigned r = (u + 0x7fffu + ((u >> 16) & 1u)) >> 16;   // RNE
    return (ushort)r;
}
__device__ __forceinline__ float bf2f(ushort us) {
    return __builtin_bit_cast(float, (unsigned)us << 16);
}
__device__ __forceinline__ void gload16(const void* g, void* l) {
    __builtin_amdgcn_global_load_lds((const __attribute__((address_space(1))) void*)g,
                                     (__attribute__((address_space(3))) void*)l, 16, 0, 0);
}

// ---------- prologue: bf16 transposed weights ----------
__global__ void wt_kernel(const float* __restrict__ w1, const float* __restrict__ w2,
                          ushort* __restrict__ w1t, ushort* __restrict__ w2t) {
    const int bid = blockIdx.x, tid = threadIdx.x;
    if (bid < NE) {                       // w1t[e][c] = w1[c][e]
        w1t[bid * NC + tid] = f2bf(w1[(size_t)tid * NE + bid]);
    } else {                              // w2t[c][e] = w2[e][c]
        const int c = bid - NE;
        for (int e = tid; e < NE; e += 256)
            w2t[c * NE + e] = f2bf(w2[(size_t)e * NC + c]);
    }
}

// ---------- prologue: forcing -> bf16 (same channel-major layout) ----------
__global__ void fconv_kernel(const float* __restrict__ fin, ushort* __restrict__ fout) {
    const size_t i8 = ((size_t)blockIdx.x * 256 + threadIdx.x) * 8;
    const float4 a = *reinterpret_cast<const float4*>(fin + i8);
    const float4 b = *reinterpret_cast<const float4*>(fin + i8 + 4);
    uint4 o;
    o.x = (unsigned)f2bf(a.x) | ((unsigned)f2bf(a.y) << 16);
    o.y = (unsigned)f2bf(a.z) | ((unsigned)f2bf(a.w) << 16);
    o.z = (unsigned)f2bf(b.x) | ((unsigned)f2bf(b.y) << 16);
    o.w = (unsigned)f2bf(b.z) | ((unsigned)f2bf(b.w) << 16);
    *reinterpret_cast<uint4*>(fout + i8) = o;
}

// ---------- prologue: X[m][c] bf16 from u0[b][c][hw] + per-row channel sums ----------
__global__ __launch_bounds__(256) void x0_kernel(const float* __restrict__ u,
                                                 ushort* __restrict__ X,
                                                 float* __restrict__ rowsums) {
    __shared__ ushort xs[64][264];
    const int tid = threadIdx.x;
    const int b = blockIdx.x >> 6, y = blockIdx.x & 63;
    const float* up = u + (size_t)b * NC * NHW + y * NW;
#pragma unroll
    for (int cc = 0; cc < 4; ++cc)
#pragma unroll
        for (int i = 0; i < 16; ++i) {
            const int idx = i * 256 + tid;
            const int c = idx >> 6, x = idx & 63;
            xs[x][cc * 64 + c] = f2bf(up[(size_t)(cc * 64 + c) * NHW + x]);
        }
    __syncthreads();
    ushort* Xp = X + ((size_t)b * NHW + y * NW) * NC;
    const int wv = tid >> 6, lane = tid & 63;
#pragma unroll
    for (int r = 0; r < 16; ++r) {
        const int row = wv * 16 + r;
        *reinterpret_cast<uint2*>(Xp + (size_t)row * NC + lane * 4) =
            *reinterpret_cast<const uint2*>(&xs[row][lane * 4]);
    }
    // exact fp32 row sums per channel (thread = channel)
    const float* rp = up + (size_t)tid * NHW;
    float s = 0.f;
#pragma unroll
    for (int x = 0; x < 64; ++x) s += rp[x];
    rowsums[((size_t)b * 64 + y) * NC + tid] = s;
}

// ---------- gated global memory state (pooled computed from rowsums) ----------
__global__ void h_kernel(const float* __restrict__ rowsums,
                         const float* __restrict__ wf, const float* __restrict__ bfv,
                         const float* __restrict__ wi, const float* __restrict__ biv,
                         const float* __restrict__ wc, const float* __restrict__ bcv,
                         float* __restrict__ h, const int first) {
    const int b = blockIdx.x;
    const int c = threadIdx.x;
    __shared__ float sp[NC];
    const float* rs = rowsums + (size_t)b * 64 * NC + c;
    float s = 0.f;
#pragma unroll
    for (int y = 0; y < 64; ++y) s += rs[y * NC];
    sp[c] = s * (1.f / 4096.f);
    __syncthreads();
    float af = bfv[c], ai = biv[c], ac = bcv[c];
    for (int k = 0; k < NC; ++k) {
        const float p = sp[k];
        af = fmaf(p, wf[k * NC + c], af);
        ai = fmaf(p, wi[k * NC + c], ai);
        ac = fmaf(p, wc[k * NC + c], ac);
    }
    const float f  = sigm_(af);
    const float ii = sigm_(ai);
    const float cc = tanhf(ac);
    const float hold = first ? 0.f : h[b * NC + c];
    h[b * NC + c] = hold * f + ii * cc;
}

// ---------- fully fused step: MLP(GEMM1+GEMM2) + stencil + memory + Euler + RMSNorm ----------
__global__ __launch_bounds__(256, 2) void step_kernel(
    const ushort* __restrict__ Xg, const ushort* __restrict__ w1t,
    const ushort* __restrict__ w2t, const float* __restrict__ b1,
    const float* __restrict__ b2, const float* __restrict__ uin,
    const ushort* __restrict__ forc, const float* __restrict__ dlog,
    const float* __restrict__ hbuf, const float* __restrict__ nsc,
    const float* __restrict__ p_logdt, const float* __restrict__ p_am,
    const float* __restrict__ p_af, const int do_norm,
    float* __restrict__ uout, ushort* __restrict__ Xout,
    float* __restrict__ rowsums) {
    __shared__ __align__(16) char pool[73728];
    ushort* Xs = (ushort*)pool;             // [64px][256c] swizzled, persistent
    ushort* Wb = (ushort*)(pool + 32768);   // w1 chunk [64e][256c] / w2 chunk [256c][64e]
    ushort* Hs = (ushort*)(pool + 65536);   // [64px][64e] swizzled

    const int tid = threadIdx.x;
    const int wv = tid >> 6, lane = tid & 63;
    const int r16 = lane & 15, kg = lane >> 4;
    const int work = (blockIdx.x & 7) * 64 + (blockIdx.x >> 3);   // XCD swizzle: batch per XCD
    const int b = work >> 6, y = work & 63;
    const int m0 = work * 64;

    // ---- stage X tile (own 64 px rows) ----
#pragma unroll
    for (int i = 0; i < 8; ++i) {
        const int idx = i * 256 + tid, row = idx >> 5, s = idx & 31;
        gload16(Xg + (size_t)(m0 + row) * NC + ((s ^ (row & 7)) << 3), Xs + idx * 8);
    }

    f32x4 acc2[4][4];   // [ct c-tile][p px-tile]; wave's c-slice = wv*64
#pragma unroll
    for (int ct = 0; ct < 4; ++ct)
#pragma unroll
        for (int p = 0; p < 4; ++p) acc2[ct][p] = (f32x4){0.f, 0.f, 0.f, 0.f};

    // ---- e-chunk loop: GEMM1 (64e x 64px) -> GELU -> Hs -> GEMM2 accumulate ----
    for (int ec = 0; ec < 8; ++ec) {
        __syncthreads();   // Wb/Hs consumers of prev iter done; Xs stage drained (ec=0)
#pragma unroll
        for (int i = 0; i < 8; ++i) {      // stage w1 chunk [64e][256c]
            const int idx = i * 256 + tid, row = idx >> 5, s = idx & 31;
            gload16(w1t + (size_t)(ec * 64 + row) * NC + ((s ^ (row & 7)) << 3),
                    Wb + idx * 8);
        }
        __syncthreads();
        // GEMM1: D1[e][px], A = w1 rows(e), B = X rows(px); wave owns e-tile wv
        f32x4 acc1[4];
#pragma unroll
        for (int p = 0; p < 4; ++p) acc1[p] = (f32x4){0.f, 0.f, 0.f, 0.f};
#pragma unroll
        for (int kk = 0; kk < 8; ++kk) {
            const int g = kk * 4 + kg;
            const int ra = wv * 16 + r16;
            const bfrag8 a = *(const bfrag8*)(Wb + ra * 256 + ((g ^ (ra & 7)) << 3));
#pragma unroll
            for (int p = 0; p < 4; ++p) {
                const int rb = p * 16 + r16;
                const bfrag8 bb = *(const bfrag8*)(Xs + rb * 256 + ((g ^ (rb & 7)) << 3));
                acc1[p] = __builtin_amdgcn_mfma_f32_16x16x32_bf16(a, bb, acc1[p], 0, 0, 0);
            }
        }
        __syncthreads();   // w1 chunk reads done (Wb about to be overwritten by w2)
        // GELU -> Hs[px][e] (swizzled); lane holds e = ec*64+wv*16+kg*4+j, px = p*16+r16
        const float4 b1v = *(const float4*)(b1 + ec * 64 + wv * 16 + kg * 4);
        const float bj[4] = {b1v.x, b1v.y, b1v.z, b1v.w};
#pragma unroll
        for (int p = 0; p < 4; ++p) {
            ushort4 hv;
            hv.x = f2bf(gelu_(acc1[p][0] + bj[0]));
            hv.y = f2bf(gelu_(acc1[p][1] + bj[1]));
            hv.z = f2bf(gelu_(acc1[p][2] + bj[2]));
            hv.w = f2bf(gelu_(acc1[p][3] + bj[3]));
            const int px = p * 16 + r16;
            const int gH = wv * 2 + (kg >> 1);
            *(ushort4*)(Hs + px * 64 + ((gH ^ (px & 7)) << 3) + ((kg & 1) << 2)) = hv;
        }
#pragma unroll
        for (int i = 0; i < 8; ++i) {      // stage w2 chunk [256c][64e] (overlay Wb)
            const int idx = i * 256 + tid, row = idx >> 3, s = idx & 7;
            gload16(w2t + (size_t)row * NE + ec * 64 + ((s ^ (row & 7)) << 3),
                    Wb + idx * 8);
        }
        __syncthreads();   // Hs + w2 chunk ready
        // GEMM2: react[c][px] += , A = w2 rows(c), B = Hs rows(px)
#pragma unroll
        for (int kk = 0; kk < 2; ++kk) {
            const int g = kk * 4 + kg;
            bfrag8 bfr[4];
#pragma unroll
            for (int p = 0; p < 4; ++p) {
                const int rb = p * 16 + r16;
                bfr[p] = *(const bfrag8*)(Hs + rb * 64 + ((g ^ (rb & 7)) << 3));
            }
#pragma unroll
            for (int ct = 0; ct < 4; ++ct) {
                const int ra = wv * 64 + ct * 16 + r16;
                const bfrag8 a = *(const bfrag8*)(Wb + ra * 64 + ((g ^ (ra & 7)) << 3));
#pragma unroll
                for (int p = 0; p < 4; ++p)
                    acc2[ct][p] = __builtin_amdgcn_mfma_f32_16x16x32_bf16(a, bfr[p],
                                                                          acc2[ct][p], 0, 0, 0);
            }
        }
    }

    // ---- epilogue: dump react -> trh (2 halves), stencil + Euler ----
    float* trh = (float*)pool;                     // [128][68] f32
    float* su  = (float*)(pool + 34816);           // [64][68] f32
    const int eg = tid >> 4, pg = tid & 15, x0p = pg * 4;
    const float dt = fminf(fmaxf(expf(p_logdt[0]), 0.01f), 0.3f);
    const float am = p_am[0], afc = p_af[0];
    const float* ub = uin + (size_t)b * NC * NHW;
    const ushort* frow = forc + (size_t)b * NC * NHW + (size_t)y * NW;

    float unew[4][4][4];   // [ch][jc][ip]

#pragma unroll
    for (int h2 = 0; h2 < 2; ++h2) {
        __syncthreads();                 // protect trh region (GEMM bufs / prev half)
        if ((wv >> 1) == h2) {
            // lane holds c = wv*64 + ct*16 + kg*4 + j ; px = p*16 + r16
#pragma unroll
            for (int ct = 0; ct < 4; ++ct)
#pragma unroll
                for (int p = 0; p < 4; ++p)
#pragma unroll
                    for (int j = 0; j < 4; ++j)
                        trh[((wv & 1) * 64 + ct * 16 + kg * 4 + j) * 68 + p * 16 + r16] =
                            acc2[ct][p][j];
        }
#pragma unroll
        for (int chi = 0; chi < 2; ++chi) {
            const int ch = h2 * 2 + chi;
            __syncthreads();             // trh ready / prev su reads done
#pragma unroll
            for (int i = 0; i < 16; ++i) {
                const int idx = i * 256 + tid;
                const int r = idx >> 6, q = idx & 63;
                su[r * 68 + q] = ub[(size_t)(ch * 64 + r) * NHW + (size_t)y * NW + q];
            }
            __syncthreads();
#pragma unroll
            for (int jc = 0; jc < 4; ++jc) {
                const int cc = eg * 4 + jc;
                const int c = ch * 64 + cc;
                const float co0 = 0.25f * sigm_(dlog[c]);
                const float co1 = 0.25f * sigm_(dlog[NC + c]);
                const float co2 = 0.25f * sigm_(dlog[2 * NC + c]);
                const float hterm = am * hbuf[b * NC + c];
                const float b2v = b2[c];
                const float* up = ub + (size_t)c * NHW;

                float ym[6][4];
                const int dy[6] = {-1, 1, -2, 2, -4, 4};
#pragma unroll
                for (int n = 0; n < 6; ++n) {
                    int ry = y + dy[n];
                    ry = ry < 0 ? -ry : (ry > 63 ? 126 - ry : ry);
                    const float4 t = *reinterpret_cast<const float4*>(up + (size_t)ry * NW + x0p);
                    ym[n][0] = t.x; ym[n][1] = t.y; ym[n][2] = t.z; ym[n][3] = t.w;
                }
                const uint2 fr = *reinterpret_cast<const uint2*>(frow + (size_t)c * NHW + x0p);
                float fv[4];
                fv[0] = bf2f((ushort)(fr.x & 0xffff));
                fv[1] = bf2f((ushort)(fr.x >> 16));
                fv[2] = bf2f((ushort)(fr.y & 0xffff));
                fv[3] = bf2f((ushort)(fr.y >> 16));
                const f32x4 rv = *reinterpret_cast<const f32x4*>(&trh[(chi * 64 + cc) * 68 + x0p]);
#pragma unroll
                for (int ip = 0; ip < 4; ++ip) {
                    const int x = x0p + ip;
                    const float uc = su[cc * 68 + x];
                    int xm, xp2;
                    float dsum = 0.f, lap;
                    xm = x - 1; xm = xm < 0 ? -xm : xm;
                    xp2 = x + 1; xp2 = xp2 > 63 ? 126 - xp2 : xp2;
                    lap = su[cc * 68 + xm] + su[cc * 68 + xp2] + ym[0][ip] + ym[1][ip] - 4.f * uc;
                    dsum = fmaf(co0, lap, dsum);
                    xm = x - 2; xm = xm < 0 ? -xm : xm;
                    xp2 = x + 2; xp2 = xp2 > 63 ? 126 - xp2 : xp2;
                    lap = su[cc * 68 + xm] + su[cc * 68 + xp2] + ym[2][ip] + ym[3][ip] - 4.f * uc;
                    dsum = fmaf(co1, lap, dsum);
                    xm = x - 4; xm = xm < 0 ? -xm : xm;
                    xp2 = x + 4; xp2 = xp2 > 63 ? 126 - xp2 : xp2;
                    lap = su[cc * 68 + xm] + su[cc * 68 + xp2] + ym[4][ip] + ym[5][ip] - 4.f * uc;
                    dsum = fmaf(co2, lap, dsum);

                    const float du_ = dsum + rv[ip] + b2v + hterm + afc * fv[ip];
                    unew[ch][jc][ip] = uc + dt * du_;
                }
            }
        }
    }

    // ---- RMSNorm over channels ----
    float* redc = (float*)(pool + 34816);          // [16][68] (overlays su)
    float* inv64p = (float*)(pool + 39168);        // [64]
    if (do_norm) {
        float ps[4] = {0.f, 0.f, 0.f, 0.f};
#pragma unroll
        for (int ch = 0; ch < 4; ++ch)
#pragma unroll
            for (int jc = 0; jc < 4; ++jc)
#pragma unroll
                for (int ip = 0; ip < 4; ++ip)
                    ps[ip] = fmaf(unew[ch][jc][ip], unew[ch][jc][ip], ps[ip]);
        __syncthreads();
        *reinterpret_cast<f32x4*>(&redc[eg * 68 + x0p]) = (f32x4){ps[0], ps[1], ps[2], ps[3]};
        __syncthreads();
        if (tid < 64) {
            float s = 0.f;
#pragma unroll
            for (int g = 0; g < 16; ++g) s += redc[g * 68 + tid];
            inv64p[tid] = 1.f / (sqrtf(s) * 0.0625f + 1e-6f);
        }
    }
    __syncthreads();   // trh reads done; inv64p ready; reuse pool front as xs

    // ---- store u_new (fp32) + bf16 X (pixel-major) + per-channel row sums ----
    ushort* xs = (ushort*)pool;                    // [64][264]
    float* sums = (float*)(pool + 36864);          // [256][16]
    float persum[4][4];
    float* uob = uout + (size_t)b * NC * NHW + (size_t)y * NW;
#pragma unroll
    for (int ch = 0; ch < 4; ++ch)
#pragma unroll
        for (int jc = 0; jc < 4; ++jc) {
            const int cc = eg * 4 + jc;
            const int c = ch * 64 + cc;
            const float ns = do_norm ? nsc[c] : 1.f;
            float vv[4];
#pragma unroll
            for (int ip = 0; ip < 4; ++ip) {
                float v = unew[ch][jc][ip];
                if (do_norm) v *= inv64p[x0p + ip] * ns;
                vv[ip] = v;
                xs[(x0p + ip) * 264 + c] = f2bf(v);
            }
            persum[ch][jc] = vv[0] + vv[1] + vv[2] + vv[3];
            float4 o; o.x = vv[0]; o.y = vv[1]; o.z = vv[2]; o.w = vv[3];
            *reinterpret_cast<float4*>(uob + (size_t)c * NHW + x0p) = o;
        }
    __syncthreads();   // xs complete; sums region free (su/inv64 dead)
#pragma unroll
    for (int ch = 0; ch < 4; ++ch)
#pragma unroll
        for (int jc = 0; jc < 4; ++jc)
            sums[(ch * 64 + eg * 4 + jc) * 16 + pg] = persum[ch][jc];
    ushort* Xp = Xout + (size_t)m0 * NC;
#pragma unroll
    for (int r = 0; r < 16; ++r) {
        const int row = wv * 16 + r;
        *reinterpret_cast<uint2*>(Xp + (size_t)row * NC + lane * 4) =
            *reinterpret_cast<const uint2*>(&xs[row * 264 + lane * 4]);
    }
    __syncthreads();
    {
        float s = 0.f;
#pragma unroll
        for (int g = 0; g < 16; ++g) s += sums[tid * 16 + g];
        rowsums[((size_t)b * 64 + y) * NC + tid] = s;
    }
}

extern "C" void kernel_launch(void* const* d_in, const int* in_sizes, int n_in,
                              void* d_out, int out_size, void* d_ws, size_t ws_size,
                              hipStream_t stream) {
    (void)in_sizes; (void)n_in; (void)out_size; (void)ws_size;
    const float* u0      = (const float*)d_in[0];
    const float* forcing = (const float*)d_in[1];
    const float* dlog    = (const float*)d_in[2];
    const float* w1      = (const float*)d_in[3];
    const float* b1      = (const float*)d_in[4];
    const float* w2      = (const float*)d_in[5];
    const float* b2      = (const float*)d_in[6];
    const float* wf      = (const float*)d_in[7];
    const float* bfv     = (const float*)d_in[8];
    const float* wi      = (const float*)d_in[9];
    const float* biv     = (const float*)d_in[10];
    const float* wc      = (const float*)d_in[11];
    const float* bcv     = (const float*)d_in[12];
    const float* nsc     = (const float*)d_in[13];
    const float* p_logdt = (const float*)d_in[14];
    const float* p_am    = (const float*)d_in[15];
    const float* p_af    = (const float*)d_in[16];

    float* uout = (float*)d_out;

    char* w = (char*)d_ws;
    float*  uA     = (float*)w;   w += (size_t)NB * NC * NHW * 4;   // 33.5 MB
    ushort* X      = (ushort*)w;  w += (size_t)NB * NHW * NC * 2;   // 16.8 MB
    ushort* forc   = (ushort*)w;  w += (size_t)NB * NC * NHW * 2;   // 16.8 MB
    ushort* w1t    = (ushort*)w;  w += (size_t)NE * NC * 2;
    ushort* w2t    = (ushort*)w;  w += (size_t)NC * NE * 2;
    float* rowsums = (float*)w;   w += (size_t)NB * NH * NC * 4;    // 512 KB
    float* hbuf    = (float*)w;   w += (size_t)NB * NC * 4;

    wt_kernel<<<768, 256, 0, stream>>>(w1, w2, w1t, w2t);
    fconv_kernel<<<4096, 256, 0, stream>>>(forcing, forc);
    x0_kernel<<<NB * NH, 256, 0, stream>>>(u0, X, rowsums);

    const float* src = u0;
    for (int t = 0; t < STEPS; ++t) {
        float* dst = (t & 1) ? uout : uA;    // t=5 -> uout
        h_kernel<<<NB, 256, 0, stream>>>(rowsums, wf, bfv, wi, biv, wc, bcv, hbuf, t == 0);
        step_kernel<<<NB * NH, 256, 0, stream>>>(X, w1t, w2t, b1, b2, src, forc, dlog,
                                                 hbuf, nsc, p_logdt, p_am, p_af,
                                                 ((t + 1) % 2) == 0, dst, X, rowsums);
        src = dst;
    }
}